// Round 4
// baseline (101.477 us; speedup 1.0000x reference)
//
#include <hip/hip_runtime.h>

#define BB 8
#define HH 256
#define WW 256
#define NTOT (BB * HH * WW)   // 524288
#define RPB 4                 // rows per block in main kernel
#define NBLK (BB * HH / RPB)  // 512

struct Accum {
  double s[5];
  unsigned int count;
};

// ---------------- Kernel 1: per-column foreground bitmasks + acc zero-init -
__global__ __launch_bounds__(256) void build_masks(
    const float* __restrict__ target, unsigned* __restrict__ masks,
    Accum* __restrict__ acc) {
  const int s = blockIdx.x;  // stripe 0..7 (rows 32s..32s+31)
  const int b = blockIdx.y;  // batch 0..7
  const int j = threadIdx.x; // column
  if (s == 0 && b == 0 && j == 0) {
#pragma unroll
    for (int q = 0; q < 5; ++q) acc->s[q] = 0.0;
    acc->count = 0u;
  }
  const float* base = target + b * (HH * WW) + s * 32 * WW + j;
  unsigned m = 0;
#pragma unroll
  for (int r = 0; r < 32; ++r)
    if (base[r * WW] > 0.5f) m |= (1u << r);
  masks[b * 2048 + s * 256 + j] = m;
}

// ------- Kernel 2: vertical EDT + pruned exact horizontal min + fused ------
// Block = RPB consecutive rows of one image. Pruning exactness: k=j gives
// dt2(j) <= g2(j), so argmin k* has |j-k*| <= d_j; scanning |delta| <= R
// with R = block_max over all RPB rows of min(d,255) is >= each row's own
// max -> exact. Last block to finish folds the global sums into the loss.
__global__ __launch_bounds__(256) void main_kernel(
    const float* __restrict__ logits, const float* __restrict__ target,
    const unsigned* __restrict__ masks, Accum* __restrict__ acc,
    float* __restrict__ out) {
  __shared__ float s_g2[RPB][WW];
  __shared__ float s_red[4 * 5];
  __shared__ int s_im[4 * 2];  // per-wave {any, rmax}

  const int g = blockIdx.x;        // 0..511
  const int b = g >> 6;            // 64 blocks per image
  const int i0 = (g & 63) * RPB;   // first row within image
  const int j = threadIdx.x;
  const int lane = j & 63, wave = j >> 6;

  // column masks (whole image column, 256 bits)
  unsigned m[8];
#pragma unroll
  for (int w = 0; w < 8; ++w) m[w] = masks[b * 2048 + w * 256 + j];
  const unsigned many = m[0] | m[1] | m[2] | m[3] | m[4] | m[5] | m[6] | m[7];

  // vertical distances for RPB rows; track scan radius
  int rmax = 0;
#pragma unroll
  for (int r = 0; r < RPB; ++r) {
    const int i = i0 + r;
    const int wi = i >> 5, rr = i & 31;
    int dUp = 1 << 30, dDn = 1 << 30;
    const unsigned cur = m[wi] >> rr;  // bits at rows >= i
    if (cur) {
      dUp = __builtin_ctz(cur);
    } else {
      int off = 32 - rr;
      for (int w2 = wi + 1; w2 < 8; ++w2, off += 32)
        if (m[w2]) { dUp = off + __builtin_ctz(m[w2]); break; }
    }
    const unsigned curd = m[wi] << (31 - rr);  // bits at rows <= i
    if (curd) {
      dDn = __builtin_clz(curd);
    } else {
      int off = rr + 1;
      for (int w2 = wi - 1; w2 >= 0; --w2, off += 32)
        if (m[w2]) { dDn = off + __builtin_clz(m[w2]); break; }
    }
    const int d = min(dUp, dDn);
    s_g2[r][j] = (d < 256) ? (float)(d * d) : 1.0e9f;
    rmax = max(rmax, min(d, 255));
  }

  const int wave_any = __any(many != 0u);
#pragma unroll
  for (int off = 32; off > 0; off >>= 1)
    rmax = max(rmax, __shfl_down(rmax, off, 64));
  if (lane == 0) { s_im[wave * 2] = wave_any; s_im[wave * 2 + 1] = rmax; }
  __syncthreads();
  const int nonempty = s_im[0] | s_im[2] | s_im[4] | s_im[6];
  const int R = max(max(s_im[1], s_im[3]), max(s_im[5], s_im[7]));

  // per-row pruned horizontal min + fused elementwise, accumulated locally
  float v0 = 0.f, v1 = 0.f, v2 = 0.f, v3 = 0.f, v4 = 0.f;
#pragma unroll
  for (int r = 0; r < RPB; ++r) {
    float mn = 1.0e30f;
    for (int dlt = -R; dlt <= R; ++dlt) {
      const int k = j + dlt;
      if ((unsigned)k < 256u)
        mn = fminf(mn, (float)(dlt * dlt) + s_g2[r][k]);
    }
    const float dt = nonempty ? sqrtf(mn) : 0.0f;

    const int idx = (b * HH + i0 + r) * WW + j;
    const float x = logits[idx];
    float t = target[idx];
    t = fminf(fmaxf(t, 0.0f), 1.0f);
    const float e = __expf(-fabsf(x));
    const float inv = 1.0f / (1.0f + e);
    const float ce = fmaxf(x, 0.0f) + __logf(1.0f + e) - x * t;
    float p = (x >= 0.0f) ? inv : e * inv;  // sigmoid
    p = fminf(fmaxf(p, 1e-6f), 1.0f - 1e-6f);
    v0 += ce; v1 += p; v2 += t; v3 += p * t; v4 += p * dt;
  }

  // block reduce (fp32) -> device f64 atomics -> last block finalizes
  float v[5] = {v0, v1, v2, v3, v4};
#pragma unroll
  for (int q = 0; q < 5; ++q) {
    float s = v[q];
#pragma unroll
    for (int off = 32; off > 0; off >>= 1) s += __shfl_down(s, off, 64);
    if (lane == 0) s_red[wave * 5 + q] = s;
  }
  __syncthreads();
  if (j == 0) {
#pragma unroll
    for (int q = 0; q < 5; ++q) {
      const float s = s_red[q] + s_red[5 + q] + s_red[10 + q] + s_red[15 + q];
      atomicAdd(&acc->s[q], (double)s);
    }
    __threadfence();
    const unsigned arrived = atomicAdd(&acc->count, 1u);
    if (arrived == NBLK - 1) {
      __threadfence();
      double sum[5];
#pragma unroll
      for (int q = 0; q < 5; ++q) sum[q] = atomicAdd(&acc->s[q], 0.0);
      const double n = (double)NTOT;
      const double ce = sum[0] / n;
      const double dice =
          1.0 - (2.0 * sum[3] + 1e-6) / (sum[1] + sum[2] + 1e-6);
      const double boundary = sum[4] / n;
      out[0] = (float)(ce + dice + 0.1 * boundary);
      out[1] = (float)ce;
      out[2] = (float)dice;
      out[3] = (float)boundary;
    }
  }
}

extern "C" void kernel_launch(void* const* d_in, const int* in_sizes, int n_in,
                              void* d_out, int out_size, void* d_ws,
                              size_t ws_size, hipStream_t stream) {
  const float* logits = (const float*)d_in[0];
  const float* target = (const float*)d_in[1];
  float* out = (float*)d_out;

  char* ws = (char*)d_ws;
  unsigned* masks = (unsigned*)ws;            // 8*2048*4 = 64 KB
  Accum* acc = (Accum*)(ws + 64 * 1024);      // 48 B, 8B-aligned

  build_masks<<<dim3(8, 8), 256, 0, stream>>>(target, masks, acc);
  main_kernel<<<NBLK, 256, 0, stream>>>(logits, target, masks, acc, out);
}

// Round 5
// 75.496 us; speedup vs baseline: 1.3441x; 1.3441x over previous
//
#include <hip/hip_runtime.h>

#define BB 8
#define HH 256
#define WW 256
#define NTOT (BB * HH * WW)   // 524288
#define RPB 4                 // rows per block in main kernel
#define NBLK (BB * HH / RPB)  // 512

// ---------------- Kernel 1: per-column foreground bitmasks + counter init --
__global__ __launch_bounds__(256) void build_masks(
    const float* __restrict__ target, unsigned* __restrict__ masks,
    unsigned* __restrict__ count) {
  const int s = blockIdx.x;  // stripe 0..7 (rows 32s..32s+31)
  const int b = blockIdx.y;  // batch 0..7
  const int j = threadIdx.x; // column
  if (s == 0 && b == 0 && j == 0) *count = 0u;  // ws is poisoned 0xAA
  const float* base = target + b * (HH * WW) + s * 32 * WW + j;
  unsigned m = 0;
#pragma unroll
  for (int r = 0; r < 32; ++r)
    if (base[r * WW] > 0.5f) m |= (1u << r);
  masks[b * 2048 + s * 256 + j] = m;
}

// ------- Kernel 2: vertical EDT + pruned exact horizontal min + fused ------
// Block = RPB consecutive rows of one image. Pruning exactness: k=j gives
// dt2(j) <= g2(j), so argmin k* has |j-k*| <= d_j; scanning |delta| <= R
// with R = block_max over all RPB rows of min(d,255) is >= each row's own
// max -> exact. Per-block partials are plain f32 stores (no contention);
// one u32 arrival counter; last-arriving block reduces all partials in f64.
__global__ __launch_bounds__(256) void main_kernel(
    const float* __restrict__ logits, const float* __restrict__ target,
    const unsigned* __restrict__ masks, float* __restrict__ partials,
    unsigned* __restrict__ count, float* __restrict__ out) {
  __shared__ float s_g2[RPB][WW];
  __shared__ float s_red[4 * 5];
  __shared__ int s_im[4 * 2];  // per-wave {any, rmax}
  __shared__ int s_last;
  __shared__ double s_dred[4 * 5];

  const int g = blockIdx.x;        // 0..511
  const int b = g >> 6;            // 64 blocks per image
  const int i0 = (g & 63) * RPB;   // first row within image
  const int j = threadIdx.x;
  const int lane = j & 63, wave = j >> 6;

  // column masks (whole image column, 256 bits)
  unsigned m[8];
#pragma unroll
  for (int w = 0; w < 8; ++w) m[w] = masks[b * 2048 + w * 256 + j];
  const unsigned many = m[0] | m[1] | m[2] | m[3] | m[4] | m[5] | m[6] | m[7];

  // vertical distances for RPB rows; track scan radius
  int rmax = 0;
#pragma unroll
  for (int r = 0; r < RPB; ++r) {
    const int i = i0 + r;
    const int wi = i >> 5, rr = i & 31;
    int dUp = 1 << 30, dDn = 1 << 30;
    const unsigned cur = m[wi] >> rr;  // bits at rows >= i
    if (cur) {
      dUp = __builtin_ctz(cur);
    } else {
      int off = 32 - rr;
      for (int w2 = wi + 1; w2 < 8; ++w2, off += 32)
        if (m[w2]) { dUp = off + __builtin_ctz(m[w2]); break; }
    }
    const unsigned curd = m[wi] << (31 - rr);  // bits at rows <= i
    if (curd) {
      dDn = __builtin_clz(curd);
    } else {
      int off = rr + 1;
      for (int w2 = wi - 1; w2 >= 0; --w2, off += 32)
        if (m[w2]) { dDn = off + __builtin_clz(m[w2]); break; }
    }
    const int d = min(dUp, dDn);
    s_g2[r][j] = (d < 256) ? (float)(d * d) : 1.0e9f;
    rmax = max(rmax, min(d, 255));
  }

  const int wave_any = __any(many != 0u);
#pragma unroll
  for (int off = 32; off > 0; off >>= 1)
    rmax = max(rmax, __shfl_down(rmax, off, 64));
  if (lane == 0) { s_im[wave * 2] = wave_any; s_im[wave * 2 + 1] = rmax; }
  __syncthreads();
  const int nonempty = s_im[0] | s_im[2] | s_im[4] | s_im[6];
  const int R = max(max(s_im[1], s_im[3]), max(s_im[5], s_im[7]));

  // per-row pruned horizontal min + fused elementwise, accumulated locally
  float v0 = 0.f, v1 = 0.f, v2 = 0.f, v3 = 0.f, v4 = 0.f;
#pragma unroll
  for (int r = 0; r < RPB; ++r) {
    float mn = 1.0e30f;
    for (int dlt = -R; dlt <= R; ++dlt) {
      const int k = j + dlt;
      if ((unsigned)k < 256u)
        mn = fminf(mn, (float)(dlt * dlt) + s_g2[r][k]);
    }
    const float dt = nonempty ? sqrtf(mn) : 0.0f;

    const int idx = (b * HH + i0 + r) * WW + j;
    const float x = logits[idx];
    float t = target[idx];
    t = fminf(fmaxf(t, 0.0f), 1.0f);
    const float e = __expf(-fabsf(x));
    const float inv = 1.0f / (1.0f + e);
    const float ce = fmaxf(x, 0.0f) + __logf(1.0f + e) - x * t;
    float p = (x >= 0.0f) ? inv : e * inv;  // sigmoid
    p = fminf(fmaxf(p, 1e-6f), 1.0f - 1e-6f);
    v0 += ce; v1 += p; v2 += t; v3 += p * t; v4 += p * dt;
  }

  // block reduce (fp32) -> per-block partial stores -> arrival counter
  float v[5] = {v0, v1, v2, v3, v4};
#pragma unroll
  for (int q = 0; q < 5; ++q) {
    float s = v[q];
#pragma unroll
    for (int off = 32; off > 0; off >>= 1) s += __shfl_down(s, off, 64);
    if (lane == 0) s_red[wave * 5 + q] = s;
  }
  __syncthreads();
  if (j == 0) {
#pragma unroll
    for (int q = 0; q < 5; ++q) {
      const float s = s_red[q] + s_red[5 + q] + s_red[10 + q] + s_red[15 + q];
      __hip_atomic_store(&partials[q * NBLK + g], s, __ATOMIC_RELAXED,
                         __HIP_MEMORY_SCOPE_AGENT);
    }
    __threadfence();  // release: partials visible device-wide before count++
    const unsigned arrived = atomicAdd(count, 1u);
    s_last = (arrived == NBLK - 1u) ? 1 : 0;
  }
  __syncthreads();

  // last-arriving block: all 256 threads reduce 512x5 partials in f64
  if (s_last) {
    __threadfence();  // acquire
    double acc[5];
#pragma unroll
    for (int q = 0; q < 5; ++q) {
      const float a = __hip_atomic_load(&partials[q * NBLK + j],
                                        __ATOMIC_RELAXED,
                                        __HIP_MEMORY_SCOPE_AGENT);
      const float bq = __hip_atomic_load(&partials[q * NBLK + 256 + j],
                                         __ATOMIC_RELAXED,
                                         __HIP_MEMORY_SCOPE_AGENT);
      acc[q] = (double)a + (double)bq;
    }
#pragma unroll
    for (int q = 0; q < 5; ++q) {
      double s = acc[q];
#pragma unroll
      for (int off = 32; off > 0; off >>= 1) s += __shfl_down(s, off, 64);
      if (lane == 0) s_dred[wave * 5 + q] = s;
    }
    __syncthreads();
    if (j == 0) {
      double sum[5];
#pragma unroll
      for (int q = 0; q < 5; ++q)
        sum[q] = s_dred[q] + s_dred[5 + q] + s_dred[10 + q] + s_dred[15 + q];
      const double n = (double)NTOT;
      const double ce = sum[0] / n;
      const double dice =
          1.0 - (2.0 * sum[3] + 1e-6) / (sum[1] + sum[2] + 1e-6);
      const double boundary = sum[4] / n;
      out[0] = (float)(ce + dice + 0.1 * boundary);
      out[1] = (float)ce;
      out[2] = (float)dice;
      out[3] = (float)boundary;
    }
  }
}

extern "C" void kernel_launch(void* const* d_in, const int* in_sizes, int n_in,
                              void* d_out, int out_size, void* d_ws,
                              size_t ws_size, hipStream_t stream) {
  const float* logits = (const float*)d_in[0];
  const float* target = (const float*)d_in[1];
  float* out = (float*)d_out;

  char* ws = (char*)d_ws;
  unsigned* masks = (unsigned*)ws;                  // 8*2048*4 = 64 KB
  float* partials = (float*)(ws + 64 * 1024);       // 5*512*4 = 10 KB
  unsigned* count = (unsigned*)(ws + 80 * 1024);    // 4 B

  build_masks<<<dim3(8, 8), 256, 0, stream>>>(target, masks, count);
  main_kernel<<<NBLK, 256, 0, stream>>>(logits, target, masks, partials,
                                        count, out);
}

// Round 6
// 68.569 us; speedup vs baseline: 1.4799x; 1.1010x over previous
//
#include <hip/hip_runtime.h>

#define BB 8
#define HH 256
#define WW 256
#define NTOT (BB * HH * WW)   // 524288
#define RPB 4                 // rows per block in main kernel
#define NBLK (BB * HH / RPB)  // 512

// ---------------- Kernel 1: per-column foreground bitmasks -----------------
__global__ __launch_bounds__(256) void build_masks(
    const float* __restrict__ target, unsigned* __restrict__ masks) {
  const int s = blockIdx.x;  // stripe 0..7 (rows 32s..32s+31)
  const int b = blockIdx.y;  // batch 0..7
  const int j = threadIdx.x; // column
  const float* base = target + b * (HH * WW) + s * 32 * WW + j;
  unsigned m = 0;
#pragma unroll
  for (int r = 0; r < 32; ++r)
    if (base[r * WW] > 0.5f) m |= (1u << r);
  masks[b * 2048 + s * 256 + j] = m;
}

// ------- Kernel 2: vertical EDT + pruned exact horizontal min + fused ------
// Block = RPB consecutive rows of one image. Pruning exactness: k=j gives
// dt2(j) <= g2(j), so any argmin k* has |j-k*| <= d_j; scanning
// |delta| <= R with R = block_max over all RPB rows of min(d,255) is >=
// each row's own max -> exact. s_g2 rows are padded with sentinel margins
// so the scan needs no bounds check. Plain f32 partial stores; no fences.
__global__ __launch_bounds__(256) void main_kernel(
    const float* __restrict__ logits, const float* __restrict__ target,
    const unsigned* __restrict__ masks,
    float* __restrict__ partials /* [5][NBLK] */) {
  __shared__ float s_g2[RPB][3 * WW];  // [pad | row | pad], sentinel-filled
  __shared__ float s_red[4 * 5];
  __shared__ int s_im[4 * 2];  // per-wave {any, rmax}

  const int g = blockIdx.x;        // 0..511
  const int b = g >> 6;            // 64 blocks per image
  const int i0 = (g & 63) * RPB;   // first row within image
  const int j = threadIdx.x;
  const int lane = j & 63, wave = j >> 6;

  // column masks (whole image column, 256 bits)
  unsigned m[8];
#pragma unroll
  for (int w = 0; w < 8; ++w) m[w] = masks[b * 2048 + w * 256 + j];
  const unsigned many = m[0] | m[1] | m[2] | m[3] | m[4] | m[5] | m[6] | m[7];

  // vertical distances for RPB rows; sentinel pads; track scan radius
  int rmax = 0;
#pragma unroll
  for (int r = 0; r < RPB; ++r) {
    const int i = i0 + r;
    const int wi = i >> 5, rr = i & 31;
    int dUp = 1 << 30, dDn = 1 << 30;
    const unsigned cur = m[wi] >> rr;  // bits at rows >= i
    if (cur) {
      dUp = __builtin_ctz(cur);
    } else {
      int off = 32 - rr;
      for (int w2 = wi + 1; w2 < 8; ++w2, off += 32)
        if (m[w2]) { dUp = off + __builtin_ctz(m[w2]); break; }
    }
    const unsigned curd = m[wi] << (31 - rr);  // bits at rows <= i
    if (curd) {
      dDn = __builtin_clz(curd);
    } else {
      int off = rr + 1;
      for (int w2 = wi - 1; w2 >= 0; --w2, off += 32)
        if (m[w2]) { dDn = off + __builtin_clz(m[w2]); break; }
    }
    const int d = min(dUp, dDn);
    s_g2[r][WW + j] = (d < 256) ? (float)(d * d) : 1.0e9f;
    s_g2[r][j] = 1.0e9f;           // left pad
    s_g2[r][2 * WW + j] = 1.0e9f;  // right pad
    rmax = max(rmax, min(d, 255));
  }

  const int wave_any = __any(many != 0u);
#pragma unroll
  for (int off = 32; off > 0; off >>= 1)
    rmax = max(rmax, __shfl_down(rmax, off, 64));
  if (lane == 0) { s_im[wave * 2] = wave_any; s_im[wave * 2 + 1] = rmax; }
  __syncthreads();
  const int nonempty = s_im[0] | s_im[2] | s_im[4] | s_im[6];
  const int R = max(max(s_im[1], s_im[3]), max(s_im[5], s_im[7]));

  // per-row pruned horizontal min + fused elementwise, accumulated locally
  float v0 = 0.f, v1 = 0.f, v2 = 0.f, v3 = 0.f, v4 = 0.f;
#pragma unroll
  for (int r = 0; r < RPB; ++r) {
    float mn = 1.0e30f;
    const float* gp = &s_g2[r][WW + j];
    for (int dlt = -R; dlt <= R; ++dlt)
      mn = fminf(mn, (float)(dlt * dlt) + gp[dlt]);
    const float dt = nonempty ? sqrtf(mn) : 0.0f;

    const int idx = (b * HH + i0 + r) * WW + j;
    const float x = logits[idx];
    float t = target[idx];
    t = fminf(fmaxf(t, 0.0f), 1.0f);
    const float e = __expf(-fabsf(x));
    const float inv = 1.0f / (1.0f + e);
    const float ce = fmaxf(x, 0.0f) + __logf(1.0f + e) - x * t;
    float p = (x >= 0.0f) ? inv : e * inv;  // sigmoid
    p = fminf(fmaxf(p, 1e-6f), 1.0f - 1e-6f);
    v0 += ce; v1 += p; v2 += t; v3 += p * t; v4 += p * dt;
  }

  // block reduce (fp32) -> plain per-block partial stores
  float v[5] = {v0, v1, v2, v3, v4};
#pragma unroll
  for (int q = 0; q < 5; ++q) {
    float s = v[q];
#pragma unroll
    for (int off = 32; off > 0; off >>= 1) s += __shfl_down(s, off, 64);
    if (lane == 0) s_red[wave * 5 + q] = s;
  }
  __syncthreads();
  if (j == 0) {
#pragma unroll
    for (int q = 0; q < 5; ++q)
      partials[q * NBLK + g] =
          s_red[q] + s_red[5 + q] + s_red[10 + q] + s_red[15 + q];
  }
}

// ---------------- Kernel 3: final reduction (double) + loss math -----------
__global__ __launch_bounds__(256) void finalize(
    const float* __restrict__ partials, float* __restrict__ out) {
  __shared__ double s_red[4 * 5];
  const int j = threadIdx.x;  // 256 threads
  const int lane = j & 63, wave = j >> 6;
  double acc[5];
#pragma unroll
  for (int q = 0; q < 5; ++q)
    acc[q] = (double)partials[q * NBLK + j] +
             (double)partials[q * NBLK + 256 + j];
#pragma unroll
  for (int q = 0; q < 5; ++q) {
    double s = acc[q];
#pragma unroll
    for (int off = 32; off > 0; off >>= 1) s += __shfl_down(s, off, 64);
    if (lane == 0) s_red[wave * 5 + q] = s;
  }
  __syncthreads();
  if (j == 0) {
    double sum[5];
#pragma unroll
    for (int q = 0; q < 5; ++q)
      sum[q] = s_red[q] + s_red[5 + q] + s_red[10 + q] + s_red[15 + q];
    const double n = (double)NTOT;
    const double ce = sum[0] / n;
    const double dice = 1.0 - (2.0 * sum[3] + 1e-6) / (sum[1] + sum[2] + 1e-6);
    const double boundary = sum[4] / n;
    out[0] = (float)(ce + dice + 0.1 * boundary);
    out[1] = (float)ce;
    out[2] = (float)dice;
    out[3] = (float)boundary;
  }
}

extern "C" void kernel_launch(void* const* d_in, const int* in_sizes, int n_in,
                              void* d_out, int out_size, void* d_ws,
                              size_t ws_size, hipStream_t stream) {
  const float* logits = (const float*)d_in[0];
  const float* target = (const float*)d_in[1];
  float* out = (float*)d_out;

  char* ws = (char*)d_ws;
  unsigned* masks = (unsigned*)ws;              // 8*2048*4 = 64 KB
  float* partials = (float*)(ws + 64 * 1024);   // 5*512*4 = 10 KB

  build_masks<<<dim3(8, 8), 256, 0, stream>>>(target, masks);
  main_kernel<<<NBLK, 256, 0, stream>>>(logits, target, masks, partials);
  finalize<<<1, 256, 0, stream>>>(partials, out);
}